// Round 11
// baseline (195.101 us; speedup 1.0000x reference)
//
#include <hip/hip_runtime.h>
#include <hip/hip_bf16.h>
#include <math.h>
#include <string.h>

#define B 16
#define HB 8                      // half-batch for phased schedule
#define C 512
#define L 8192
#define PP 128
#define TL 32
#define TPB 2                     // tiles per block
#define NBLK (L / (TL * TPB))     // 128 partial-blocks per batch
#define LN_EPS 1e-5f

typedef float fx4 __attribute__((ext_vector_type(4)));

static __device__ inline unsigned int pack_bf2(float a, float b) {
  __hip_bfloat16 ha = __float2bfloat16(a), hb = __float2bfloat16(b);
  unsigned short ua, ub;
  memcpy(&ua, &ha, 2); memcpy(&ub, &hb, 2);
  return ((unsigned int)ub << 16) | ua;
}
static __device__ inline float bf_lo(unsigned int u) {
  unsigned int v = u << 16; float f; memcpy(&f, &v, 4); return f;
}
static __device__ inline float bf_hi(unsigned int u) {
  unsigned int v = u & 0xffff0000u; float f; memcpy(&f, &v, 4); return f;
}

// ---- Fused: scores + per-block flash softmax + partial context (round-9 body). ----
__global__ __launch_bounds__(256, 4) void k_fused(
    const float* __restrict__ x, const float* __restrict__ cw,
    float* __restrict__ part_pc, float* __restrict__ part_m, float* __restrict__ part_z,
    int b0) {
  const int b = b0 + blockIdx.y;
  const int blk = blockIdx.x;
  const int tid = threadIdx.x;
  const int q = tid & 7;
  const int r = tid >> 3;          // 0..31
  const int lane = tid & 63;
  const int w = tid >> 6;          // wave 0..3

  __shared__ unsigned int xt[C][17];    // 34 ushorts/row (68 B stride, bank-spread)
  __shared__ float scw[C];
  __shared__ float sred[4][TL];
  __shared__ float pw[TL];
  __shared__ float s_m, s_z, s_resc;

  scw[tid] = cw[tid];
  scw[tid + 256] = cw[tid + 256];
  if (tid == 0) { s_m = -INFINITY; s_z = 0.f; }

  float pc0 = 0.f, pc1 = 0.f;
  const size_t xbase = (size_t)b * C * L;

  for (int t = 0; t < TPB; ++t) {
    const int l0 = (blk * TPB + t) * TL;
    const float4* xb4 = (const float4*)(x + xbase + l0);
    __syncthreads();                      // xt/sred/pw reuse; scw/s_m visible at t=0

    // Phase 1: stream 16 float4, score partials + bf16 stash.
    float sp0 = 0.f, sp1 = 0.f, sp2 = 0.f, sp3 = 0.f;
    #pragma unroll
    for (int i = 0; i < 16; ++i) {
      const int c = r + 32 * i;
      const float4 v = xb4[(size_t)c * (L / 4) + q];
      const float wc = scw[c];
      sp0 += v.x * wc; sp1 += v.y * wc; sp2 += v.z * wc; sp3 += v.w * wc;
      xt[c][2 * q]     = pack_bf2(v.x, v.y);
      xt[c][2 * q + 1] = pack_bf2(v.z, v.w);
    }
    // reduce over r within wave (lane bits 3..5)
    #pragma unroll
    for (int m = 8; m <= 32; m <<= 1) {
      sp0 += __shfl_xor(sp0, m); sp1 += __shfl_xor(sp1, m);
      sp2 += __shfl_xor(sp2, m); sp3 += __shfl_xor(sp3, m);
    }
    if (lane < 8) {
      sred[w][4 * lane + 0] = sp0;
      sred[w][4 * lane + 1] = sp1;
      sred[w][4 * lane + 2] = sp2;
      sred[w][4 * lane + 3] = sp3;
    }
    __syncthreads();

    // Wave 0 (lanes 0..31): finalize 32 scores, online softmax update.
    if (tid < 32) {
      float s = sred[0][tid] + sred[1][tid] + sred[2][tid] + sred[3][tid];
      float m = s;
      #pragma unroll
      for (int off = 16; off; off >>= 1) m = fmaxf(m, __shfl_xor(m, off, 32));
      const float mold = s_m;
      const float mnew = fmaxf(mold, m);
      const float p = __expf(s - mnew);
      float z = p;
      #pragma unroll
      for (int off = 16; off; off >>= 1) z += __shfl_xor(z, off, 32);
      pw[tid] = p;
      if (tid == 0) {
        const float e = __expf(mold - mnew);   // t=0: exp(-inf)=0 zeroes acc
        s_resc = e;
        s_z = s_z * e + z;
        s_m = mnew;
      }
    }
    __syncthreads();

    // Phase 2: thread-per-channel row sweep from LDS; 2 private accumulators.
    const float resc = s_resc;
    float a0 = 0.f, a1 = 0.f;
    #pragma unroll
    for (int j = 0; j < 16; ++j) {
      const float wl = pw[2 * j], wh = pw[2 * j + 1];
      const unsigned int u0 = xt[tid][j];
      const unsigned int u1 = xt[tid + 256][j];
      a0 += bf_lo(u0) * wl + bf_hi(u0) * wh;
      a1 += bf_lo(u1) * wl + bf_hi(u1) * wh;
    }
    pc0 = pc0 * resc + a0;
    pc1 = pc1 * resc + a1;
  }

  float* dst = part_pc + (size_t)(b * NBLK + blk) * C;
  dst[tid] = pc0;
  dst[tid + 256] = pc1;
  if (tid == 0) {
    part_m[b * NBLK + blk] = s_m;
    part_z[b * NBLK + blk] = s_z;
  }
}

// ---- Tail: flash-combine 128 partials -> context -> MLP(LN,ReLU) -> add_term ----
__global__ void k_tail(const float* __restrict__ part_pc, const float* __restrict__ part_m,
                       const float* __restrict__ part_z,
                       const float* __restrict__ w1, const float* __restrict__ b1,
                       const float* __restrict__ lnw, const float* __restrict__ lnb,
                       const float* __restrict__ w2, const float* __restrict__ b2,
                       float* __restrict__ add_term, int b0) {
  const int b = b0 + blockIdx.x;
  const int tid = threadIdx.x;   // 512 threads
  __shared__ float se[NBLK];
  __shared__ float sMZ[2];
  __shared__ float sctx[C];
  __shared__ float st[PP];

  const float* pm = part_m + b * NBLK;
  const float* pz = part_z + b * NBLK;

  if (tid < 64) {
    const float m0 = pm[tid], m1 = pm[tid + 64];
    float mm = fmaxf(m0, m1);
    #pragma unroll
    for (int off = 32; off; off >>= 1) mm = fmaxf(mm, __shfl_xor(mm, off));
    float z = pz[tid] * __expf(m0 - mm) + pz[tid + 64] * __expf(m1 - mm);
    #pragma unroll
    for (int off = 32; off; off >>= 1) z += __shfl_xor(z, off);
    if (tid == 0) { sMZ[0] = mm; sMZ[1] = z; }
  }
  __syncthreads();
  const float M = sMZ[0];
  const float Zinv = 1.f / sMZ[1];
  if (tid < NBLK) se[tid] = __expf(pm[tid] - M) * Zinv;
  __syncthreads();

  // context[b, tid]
  float acc = 0.f;
  const float* pp = part_pc + (size_t)b * NBLK * C + tid;
  #pragma unroll 4
  for (int t = 0; t < NBLK; ++t) acc += pp[(size_t)t * C] * se[t];
  sctx[tid] = acc;
  __syncthreads();

  // t = w1 @ ctx + b1 (4 threads per output p)
  {
    const int p = tid >> 2;
    const int qq = tid & 3;
    const float* w1r = w1 + (size_t)p * C + qq * 128;
    const float* cx = &sctx[qq * 128];
    float a = 0.f;
    #pragma unroll 8
    for (int cc = 0; cc < 128; ++cc) a += w1r[cc] * cx[cc];
    a += __shfl_xor(a, 1);
    a += __shfl_xor(a, 2);
    if (qq == 0) st[p] = a + b1[p];
  }
  __syncthreads();

  // LayerNorm over P + ReLU
  float tv = 0.f;
  if (tid < PP) {
    float mu = 0.f;
    #pragma unroll 8
    for (int pi = 0; pi < PP; ++pi) mu += st[pi];
    mu *= (1.f / PP);
    float var = 0.f;
    #pragma unroll 8
    for (int pi = 0; pi < PP; ++pi) { const float d = st[pi] - mu; var += d * d; }
    var *= (1.f / PP);
    tv = (st[tid] - mu) * rsqrtf(var + LN_EPS) * lnw[tid] + lnb[tid];
    tv = fmaxf(tv, 0.f);
  }
  __syncthreads();
  if (tid < PP) st[tid] = tv;
  __syncthreads();

  // add_term[c] = w2[c,:] @ t + b2[c]
  float a2 = b2[tid];
  const float* w2r = w2 + (size_t)tid * PP;
  #pragma unroll 8
  for (int pi = 0; pi < PP; ++pi) a2 += w2r[pi] * st[pi];
  add_term[b * C + tid] = a2;
}

// ---- out[row,:] = x[row,:] + add_term[row] for one half-batch; NT stores. ----
__global__ void k_add(const float* __restrict__ x, const float* __restrict__ at,
                      float* __restrict__ out, int b0) {
  const int bc = b0 * C + blockIdx.x;
  const float a = at[bc];
  const fx4* xr = (const fx4*)(x + (size_t)bc * L);
  fx4* orow = (fx4*)(out + (size_t)bc * L);
  #pragma unroll 4
  for (int i = threadIdx.x; i < L / 4; i += 256) {
    fx4 v = xr[i];
    v = v + a;
    __builtin_nontemporal_store(v, &orow[i]);
  }
}

extern "C" void kernel_launch(void* const* d_in, const int* in_sizes, int n_in,
                              void* d_out, int out_size, void* d_ws, size_t ws_size,
                              hipStream_t stream) {
  const float* x   = (const float*)d_in[0];
  const float* cw  = (const float*)d_in[1];
  // d_in[2] (conv_mask_b) cancels exactly under softmax shift-invariance.
  const float* w1  = (const float*)d_in[3];
  const float* b1  = (const float*)d_in[4];
  const float* lnw = (const float*)d_in[5];
  const float* lnb = (const float*)d_in[6];
  const float* w2  = (const float*)d_in[7];
  const float* b2  = (const float*)d_in[8];
  float* out = (float*)d_out;

  char* ws = (char*)d_ws;
  float* part_pc  = (float*)ws;                                  // B*NBLK*C = 4 MB
  float* part_m   = (float*)(ws + (size_t)B * NBLK * C * 4);     // 8 KB
  float* part_z   = part_m + B * NBLK;
  float* add_term = part_z + B * NBLK;                           // 32 KB

  // Half-batch phased schedule: each 128 MB half of x is re-read (by k_add)
  // while it still fits in the 256 MiB L3 alongside the other half.
  k_fused<<<dim3(NBLK, HB), 256, 0, stream>>>(x, cw, part_pc, part_m, part_z, 0);
  k_fused<<<dim3(NBLK, HB), 256, 0, stream>>>(x, cw, part_pc, part_m, part_z, HB);
  k_tail<<<HB, 512, 0, stream>>>(part_pc, part_m, part_z,
                                 w1, b1, lnw, lnb, w2, b2, add_term, HB);
  k_add<<<HB * C, 256, 0, stream>>>(x, add_term, out, HB);   // x[8..15] L3-hot
  k_tail<<<HB, 512, 0, stream>>>(part_pc, part_m, part_z,
                                 w1, b1, lnw, lnb, w2, b2, add_term, 0);
  k_add<<<HB * C, 256, 0, stream>>>(x, add_term, out, 0);    // x[0..7] still resident
}

// Round 14
// 184.694 us; speedup vs baseline: 1.0563x; 1.0563x over previous
//
#include <hip/hip_runtime.h>
#include <hip/hip_bf16.h>
#include <math.h>
#include <string.h>

#define B 16
#define C 512
#define L 8192
#define PP 128
#define TL 32
#define TPB 2                     // tiles per block
#define NBLK (L / (TL * TPB))     // 128 partial-blocks per batch
#define LN_EPS 1e-5f

typedef float fx4 __attribute__((ext_vector_type(4)));

static __device__ inline unsigned int pack_bf2(float a, float b) {
  __hip_bfloat16 ha = __float2bfloat16(a), hb = __float2bfloat16(b);
  unsigned short ua, ub;
  memcpy(&ua, &ha, 2); memcpy(&ub, &hb, 2);
  return ((unsigned int)ub << 16) | ua;
}
static __device__ inline float bf_lo(unsigned int u) {
  unsigned int v = u << 16; float f; memcpy(&f, &v, 4); return f;
}
static __device__ inline float bf_hi(unsigned int u) {
  unsigned int v = u & 0xffff0000u; float f; memcpy(&f, &v, 4); return f;
}

// ---- Fused: scores + per-block flash softmax + partial context (round-9 body). ----
__global__ __launch_bounds__(256, 4) void k_fused(
    const float* __restrict__ x, const float* __restrict__ cw,
    float* __restrict__ part_pc, float* __restrict__ part_m, float* __restrict__ part_z) {
  const int b = blockIdx.y;
  const int blk = blockIdx.x;
  const int tid = threadIdx.x;
  const int q = tid & 7;
  const int r = tid >> 3;          // 0..31
  const int lane = tid & 63;
  const int w = tid >> 6;          // wave 0..3

  __shared__ unsigned int xt[C][17];    // 34 ushorts/row (68 B stride, bank-spread)
  __shared__ float scw[C];
  __shared__ float sred[4][TL];
  __shared__ float pw[TL];
  __shared__ float s_m, s_z, s_resc;

  scw[tid] = cw[tid];
  scw[tid + 256] = cw[tid + 256];
  if (tid == 0) { s_m = -INFINITY; s_z = 0.f; }

  float pc0 = 0.f, pc1 = 0.f;
  const size_t xbase = (size_t)b * C * L;

  for (int t = 0; t < TPB; ++t) {
    const int l0 = (blk * TPB + t) * TL;
    const float4* xb4 = (const float4*)(x + xbase + l0);
    __syncthreads();                      // xt/sred/pw reuse; scw/s_m visible at t=0

    // Phase 1: stream 16 float4, score partials + bf16 stash (consume immediately).
    float sp0 = 0.f, sp1 = 0.f, sp2 = 0.f, sp3 = 0.f;
    #pragma unroll
    for (int i = 0; i < 16; ++i) {
      const int c = r + 32 * i;
      const float4 v = xb4[(size_t)c * (L / 4) + q];
      const float wc = scw[c];
      sp0 += v.x * wc; sp1 += v.y * wc; sp2 += v.z * wc; sp3 += v.w * wc;
      xt[c][2 * q]     = pack_bf2(v.x, v.y);
      xt[c][2 * q + 1] = pack_bf2(v.z, v.w);
    }
    // reduce over r within wave (lane bits 3..5)
    #pragma unroll
    for (int m = 8; m <= 32; m <<= 1) {
      sp0 += __shfl_xor(sp0, m); sp1 += __shfl_xor(sp1, m);
      sp2 += __shfl_xor(sp2, m); sp3 += __shfl_xor(sp3, m);
    }
    if (lane < 8) {
      sred[w][4 * lane + 0] = sp0;
      sred[w][4 * lane + 1] = sp1;
      sred[w][4 * lane + 2] = sp2;
      sred[w][4 * lane + 3] = sp3;
    }
    __syncthreads();

    // Wave 0 (lanes 0..31): finalize 32 scores, online softmax update.
    if (tid < 32) {
      float s = sred[0][tid] + sred[1][tid] + sred[2][tid] + sred[3][tid];
      float m = s;
      #pragma unroll
      for (int off = 16; off; off >>= 1) m = fmaxf(m, __shfl_xor(m, off, 32));
      const float mold = s_m;
      const float mnew = fmaxf(mold, m);
      const float p = __expf(s - mnew);
      float z = p;
      #pragma unroll
      for (int off = 16; off; off >>= 1) z += __shfl_xor(z, off, 32);
      pw[tid] = p;
      if (tid == 0) {
        const float e = __expf(mold - mnew);   // t=0: exp(-inf)=0 zeroes acc
        s_resc = e;
        s_z = s_z * e + z;
        s_m = mnew;
      }
    }
    __syncthreads();

    // Phase 2: thread-per-channel row sweep from LDS; 2 private accumulators.
    const float resc = s_resc;
    float a0 = 0.f, a1 = 0.f;
    #pragma unroll
    for (int j = 0; j < 16; ++j) {
      const float wl = pw[2 * j], wh = pw[2 * j + 1];
      const unsigned int u0 = xt[tid][j];
      const unsigned int u1 = xt[tid + 256][j];
      a0 += bf_lo(u0) * wl + bf_hi(u0) * wh;
      a1 += bf_lo(u1) * wl + bf_hi(u1) * wh;
    }
    pc0 = pc0 * resc + a0;
    pc1 = pc1 * resc + a1;
  }

  float* dst = part_pc + (size_t)(b * NBLK + blk) * C;
  dst[tid] = pc0;
  dst[tid + 256] = pc1;
  if (tid == 0) {
    part_m[b * NBLK + blk] = s_m;
    part_z[b * NBLK + blk] = s_z;
  }
}

// ---- Tail: flash-combine 128 partials -> context -> MLP(LN,ReLU) -> add_term ----
__global__ void k_tail(const float* __restrict__ part_pc, const float* __restrict__ part_m,
                       const float* __restrict__ part_z,
                       const float* __restrict__ w1, const float* __restrict__ b1,
                       const float* __restrict__ lnw, const float* __restrict__ lnb,
                       const float* __restrict__ w2, const float* __restrict__ b2,
                       float* __restrict__ add_term) {
  const int b = blockIdx.x;
  const int tid = threadIdx.x;   // 512 threads
  __shared__ float se[NBLK];
  __shared__ float sMZ[2];
  __shared__ float sctx[C];
  __shared__ float st[PP];

  const float* pm = part_m + b * NBLK;
  const float* pz = part_z + b * NBLK;

  if (tid < 64) {
    const float m0 = pm[tid], m1 = pm[tid + 64];
    float mm = fmaxf(m0, m1);
    #pragma unroll
    for (int off = 32; off; off >>= 1) mm = fmaxf(mm, __shfl_xor(mm, off));
    float z = pz[tid] * __expf(m0 - mm) + pz[tid + 64] * __expf(m1 - mm);
    #pragma unroll
    for (int off = 32; off; off >>= 1) z += __shfl_xor(z, off);
    if (tid == 0) { sMZ[0] = mm; sMZ[1] = z; }
  }
  __syncthreads();
  const float M = sMZ[0];
  const float Zinv = 1.f / sMZ[1];
  if (tid < NBLK) se[tid] = __expf(pm[tid] - M) * Zinv;
  __syncthreads();

  // context[b, tid]
  float acc = 0.f;
  const float* pp = part_pc + (size_t)b * NBLK * C + tid;
  #pragma unroll 4
  for (int t = 0; t < NBLK; ++t) acc += pp[(size_t)t * C] * se[t];
  sctx[tid] = acc;
  __syncthreads();

  // t = w1 @ ctx + b1 (4 threads per output p)
  {
    const int p = tid >> 2;
    const int qq = tid & 3;
    const float* w1r = w1 + (size_t)p * C + qq * 128;
    const float* cx = &sctx[qq * 128];
    float a = 0.f;
    #pragma unroll 8
    for (int cc = 0; cc < 128; ++cc) a += w1r[cc] * cx[cc];
    a += __shfl_xor(a, 1);
    a += __shfl_xor(a, 2);
    if (qq == 0) st[p] = a + b1[p];
  }
  __syncthreads();

  // LayerNorm over P + ReLU
  float tv = 0.f;
  if (tid < PP) {
    float mu = 0.f;
    #pragma unroll 8
    for (int pi = 0; pi < PP; ++pi) mu += st[pi];
    mu *= (1.f / PP);
    float var = 0.f;
    #pragma unroll 8
    for (int pi = 0; pi < PP; ++pi) { const float d = st[pi] - mu; var += d * d; }
    var *= (1.f / PP);
    tv = (st[tid] - mu) * rsqrtf(var + LN_EPS) * lnw[tid] + lnb[tid];
    tv = fmaxf(tv, 0.f);
  }
  __syncthreads();
  if (tid < PP) st[tid] = tv;
  __syncthreads();

  // add_term[c] = w2[c,:] @ t + b2[c]
  float a2 = b2[tid];
  const float* w2r = w2 + (size_t)tid * PP;
  #pragma unroll 8
  for (int pi = 0; pi < PP; ++pi) a2 += w2r[pi] * st[pi];
  add_term[b * C + tid] = a2;
}

// ---- out[row,:] = x[row,:] + add_term[row]. Round-12/13 probe: PLAIN stores ----
// (nontemporal removed — never isolated; fill kernel hits 7.1 TB/s with
// regular stores, and both L3-preservation rationales for NT came up null).
__global__ void k_add(const float* __restrict__ x, const float* __restrict__ at,
                      float* __restrict__ out) {
  const int bc = (B * C - 1) - blockIdx.x;     // keep round-10 traversal (noise-equal)
  const float a = at[bc];
  const fx4* xr = (const fx4*)(x + (size_t)bc * L);
  fx4* orow = (fx4*)(out + (size_t)bc * L);
  #pragma unroll 4
  for (int i = threadIdx.x; i < L / 4; i += 256) {
    fx4 v = xr[i];
    v = v + a;
    orow[i] = v;
  }
}

extern "C" void kernel_launch(void* const* d_in, const int* in_sizes, int n_in,
                              void* d_out, int out_size, void* d_ws, size_t ws_size,
                              hipStream_t stream) {
  const float* x   = (const float*)d_in[0];
  const float* cw  = (const float*)d_in[1];
  // d_in[2] (conv_mask_b) cancels exactly under softmax shift-invariance.
  const float* w1  = (const float*)d_in[3];
  const float* b1  = (const float*)d_in[4];
  const float* lnw = (const float*)d_in[5];
  const float* lnb = (const float*)d_in[6];
  const float* w2  = (const float*)d_in[7];
  const float* b2  = (const float*)d_in[8];
  float* out = (float*)d_out;

  char* ws = (char*)d_ws;
  float* part_pc  = (float*)ws;                                  // B*NBLK*C = 4 MB
  float* part_m   = (float*)(ws + (size_t)B * NBLK * C * 4);     // 8 KB
  float* part_z   = part_m + B * NBLK;
  float* add_term = part_z + B * NBLK;                           // 32 KB

  k_fused<<<dim3(NBLK, B), 256, 0, stream>>>(x, cw, part_pc, part_m, part_z);
  k_tail<<<dim3(B), 512, 0, stream>>>(part_pc, part_m, part_z,
                                      w1, b1, lnw, lnb, w2, b2, add_term);
  k_add<<<dim3(B * C), 256, 0, stream>>>(x, add_term, out);
}